// Round 1
// baseline (1389.215 us; speedup 1.0000x reference)
//
#include <hip/hip_runtime.h>
#include <hip/hip_bf16.h>
#include <math.h>
#include <cstdint>

// ---------------------------------------------------------------------------
// 3-layer MLP (Linear+GELU ×3), bf16 MFMA compute, fp32 in/out.
// GEMM structure follows the verified m97 ladder: 128x128 block tile, BK=64,
// 4 waves x (64x64) wave tile, v_mfma_f32_16x16x32_bf16, global_load_lds(16B).
// ---------------------------------------------------------------------------

typedef __bf16 bf16_t;
typedef __attribute__((ext_vector_type(8))) __bf16 bf16x8;
typedef __attribute__((ext_vector_type(4))) float f32x4;
typedef __attribute__((ext_vector_type(4))) unsigned short u16x4;

#define BM 128
#define BN 128
#define BK 64

__device__ inline unsigned short f2bf_rne(float f) {
    unsigned int u = __builtin_bit_cast(unsigned int, f);
    u += 0x7fffu + ((u >> 16) & 1u);   // round-to-nearest-even
    return (unsigned short)(u >> 16);
}

__device__ inline float gelu_erf(float x) {
    return 0.5f * x * (1.0f + erff(x * 0.7071067811865475f));
}

// CK-proven pattern: generic->AS1/AS3 via uintptr (low 32 bits of a generic
// LDS address ARE the LDS offset). LDS dest is wave-uniform base + lane*16.
__device__ inline void gload_lds16(const void* g, void* l) {
    auto gp = reinterpret_cast<const __attribute__((address_space(1))) unsigned int*>(
        reinterpret_cast<uintptr_t>(g));
    auto lp = reinterpret_cast<__attribute__((address_space(3))) unsigned int*>(
        reinterpret_cast<uintptr_t>(l));
    __builtin_amdgcn_global_load_lds(gp, lp, 16, 0, 0);
}

// C = gelu(A[M,K] @ B[N,K]^T + bias), A fp32 or bf16, C bf16 or fp32.
template <bool A_IS_FP32, bool OUT_BF16>
__global__ __launch_bounds__(256, 2)
void gemm_bias_gelu(const void* __restrict__ Av,
                    const bf16_t* __restrict__ B,     // [N,K] bf16
                    const float* __restrict__ bias,   // [N]
                    void* __restrict__ Cv,            // [M,N]
                    int M, int N, int K)
{
    __shared__ __align__(16) bf16_t lA[BM * BK];   // 16 KiB
    __shared__ __align__(16) bf16_t lB[BN * BK];   // 16 KiB

    const int tid  = threadIdx.x;
    const int wave = tid >> 6;
    const int lane = tid & 63;
    const int lrow = lane & 15;   // MFMA row/col within 16
    const int quad = lane >> 4;   // k-group of 8

    const int row0 = blockIdx.x * BM;
    const int col0 = blockIdx.y * BN;
    const int wm = (wave >> 1) * 64;   // wave tile: 64x64
    const int wn = (wave & 1) * 64;

    f32x4 acc[4][4] = {};

    const bf16_t* Bt = B + (size_t)col0 * K;

    for (int k0 = 0; k0 < K; k0 += BK) {
        // ---- stage B tile (128 n-rows x 64 k) via global_load_lds, 16B/lane.
        // wave w covers tile rows [w*32, w*32+32) in 4 calls of 8 rows each;
        // per call: lane l -> row +(l>>3), col (l&7)*8  == LDS base + l*16B.
        {
            const bf16_t* g = Bt + (size_t)(wave * 32 + (lane >> 3)) * K + k0 + (lane & 7) * 8;
            bf16_t* l = lB + (wave * 32) * BK;
            #pragma unroll
            for (int c = 0; c < 4; ++c) {
                gload_lds16(g, l);
                g += (size_t)8 * K;
                l += 8 * BK;
            }
        }
        // ---- stage A tile
        if constexpr (!A_IS_FP32) {
            const bf16_t* Ab = (const bf16_t*)Av;
            const bf16_t* g = Ab + (size_t)(row0 + wave * 32 + (lane >> 3)) * K + k0 + (lane & 7) * 8;
            bf16_t* l = lA + (wave * 32) * BK;
            #pragma unroll
            for (int c = 0; c < 4; ++c) {
                gload_lds16(g, l);
                g += (size_t)8 * K;
                l += 8 * BK;
            }
        } else {
            // fp32 A: float4 load -> RNE bf16 -> ds_write (8B). Coalesced:
            // per c, 256 threads cover 16 rows of 64 floats contiguously.
            const float* Af = (const float*)Av;
            #pragma unroll
            for (int c = 0; c < 8; ++c) {
                const int e = c * 1024 + tid * 4;
                const int r = e >> 6;
                const int k = e & 63;
                const float4 v = *(const float4*)(Af + (size_t)(row0 + r) * K + k0 + k);
                u16x4 h;
                h.x = f2bf_rne(v.x); h.y = f2bf_rne(v.y);
                h.z = f2bf_rne(v.z); h.w = f2bf_rne(v.w);
                *(u16x4*)(lA + r * BK + k) = h;
            }
        }
        __syncthreads();   // drains vmcnt (global_load_lds) + lgkmcnt

        // ---- 32 MFMAs per K-iter (2 kk-steps of 16)
        #pragma unroll
        for (int kk = 0; kk < BK; kk += 32) {
            bf16x8 af[4], bfr[4];
            #pragma unroll
            for (int i = 0; i < 4; ++i)
                af[i] = *(const bf16x8*)(lA + (wm + i * 16 + lrow) * BK + kk + quad * 8);
            #pragma unroll
            for (int j = 0; j < 4; ++j)
                bfr[j] = *(const bf16x8*)(lB + (wn + j * 16 + lrow) * BK + kk + quad * 8);
            #pragma unroll
            for (int i = 0; i < 4; ++i) {
                #pragma unroll
                for (int j = 0; j < 4; ++j)
                    acc[i][j] = __builtin_amdgcn_mfma_f32_16x16x32_bf16(af[i], bfr[j], acc[i][j], 0, 0, 0);
            }
        }
        __syncthreads();
    }

    // ---- epilogue: bias + exact-erf GELU + store.
    // C/D layout (16x16x32): col = lane&15, row = quad*4 + reg  [m89/m91]
    #pragma unroll
    for (int j = 0; j < 4; ++j) {
        const int col = col0 + wn + j * 16 + lrow;
        const float bv = bias[col];
        #pragma unroll
        for (int i = 0; i < 4; ++i) {
            const int row = row0 + wm + i * 16 + quad * 4;
            #pragma unroll
            for (int r = 0; r < 4; ++r) {
                float v = acc[i][j][r] + bv;
                v = gelu_erf(v);
                if constexpr (OUT_BF16)
                    ((unsigned short*)Cv)[(size_t)(row + r) * N + col] = f2bf_rne(v);
                else
                    ((float*)Cv)[(size_t)(row + r) * N + col] = v;
            }
        }
    }
}

__global__ void cvt_f32_to_bf16(const float* __restrict__ s,
                                unsigned short* __restrict__ d, int n4)
{
    const int i = blockIdx.x * 256 + threadIdx.x;
    if (i < n4) {
        const float4 v = ((const float4*)s)[i];
        u16x4 h;
        h.x = f2bf_rne(v.x); h.y = f2bf_rne(v.y);
        h.z = f2bf_rne(v.z); h.w = f2bf_rne(v.w);
        ((u16x4*)d)[i] = h;
    }
}

extern "C" void kernel_launch(void* const* d_in, const int* in_sizes, int n_in,
                              void* d_out, int out_size, void* d_ws, size_t ws_size,
                              hipStream_t stream)
{
    const int BATCH = 131072, OBS = 1024, H1 = 512, H2 = 512, H3 = 256;

    const float* obs = (const float*)d_in[0];
    const float* W1  = (const float*)d_in[1];
    const float* b1  = (const float*)d_in[2];
    const float* W2  = (const float*)d_in[3];
    const float* b2  = (const float*)d_in[4];
    const float* W3  = (const float*)d_in[5];
    const float* b3  = (const float*)d_in[6];
    float* out = (float*)d_out;

    // workspace layout (~258 MB): x1 | x2 | W1b | W2b | W3b
    char* ws = (char*)d_ws;
    bf16_t* x1  = (bf16_t*)ws;                                       // BATCH*H1
    bf16_t* x2  = (bf16_t*)(ws + (size_t)BATCH * H1 * 2);            // BATCH*H2
    bf16_t* w1b = (bf16_t*)(ws + (size_t)BATCH * (H1 + H2) * 2);
    bf16_t* w2b = w1b + (size_t)H1 * OBS;
    bf16_t* w3b = w2b + (size_t)H2 * H1;

    // weight fp32 -> bf16 (tiny)
    cvt_f32_to_bf16<<<dim3((H1 * OBS / 4 + 255) / 256), 256, 0, stream>>>(W1, (unsigned short*)w1b, H1 * OBS / 4);
    cvt_f32_to_bf16<<<dim3((H2 * H1 / 4 + 255) / 256), 256, 0, stream>>>(W2, (unsigned short*)w2b, H2 * H1 / 4);
    cvt_f32_to_bf16<<<dim3((H3 * H2 / 4 + 255) / 256), 256, 0, stream>>>(W3, (unsigned short*)w3b, H3 * H2 / 4);

    // L1: obs(fp32) @ W1^T -> x1 (bf16)
    gemm_bias_gelu<true, true><<<dim3(BATCH / BM, H1 / BN), 256, 0, stream>>>(
        obs, w1b, b1, x1, BATCH, H1, OBS);
    // L2: x1 @ W2^T -> x2 (bf16)
    gemm_bias_gelu<false, true><<<dim3(BATCH / BM, H2 / BN), 256, 0, stream>>>(
        x1, w2b, b2, x2, BATCH, H2, H1);
    // L3: x2 @ W3^T -> out (fp32)
    gemm_bias_gelu<false, false><<<dim3(BATCH / BM, H3 / BN), 256, 0, stream>>>(
        x2, w3b, b3, out, BATCH, H3, H2);
}

// Round 2
// 1388.672 us; speedup vs baseline: 1.0004x; 1.0004x over previous
//
#include <hip/hip_runtime.h>
#include <hip/hip_bf16.h>
#include <math.h>
#include <cstdint>

// ---------------------------------------------------------------------------
// 3-layer MLP (Linear+GELU ×3), bf16 MFMA compute, fp32 in/out.
// m97-ladder GEMM structure + XOR-swizzled LDS layout (kills the 16-way
// bank conflict of the 128B-row-stride layout) + column-fast grid order
// (A-tile reuse through LLC).
//
// LDS layout: element (row, k) -> row*64 + ((k>>3 ^ (row&7))<<3) + (k&7).
// Compatible with global_load_lds (wave-uniform base + lane*16): lane l of
// an 8-row staging call holds row-in-group l>>3, LDS chunk l&7, so it must
// fetch GLOBAL chunk (l&7)^(l>>3) of its row — a per-lane source permute.
// ---------------------------------------------------------------------------

typedef __bf16 bf16_t;
typedef __attribute__((ext_vector_type(8))) __bf16 bf16x8;
typedef __attribute__((ext_vector_type(4))) float f32x4;
typedef __attribute__((ext_vector_type(4))) unsigned short u16x4;

#define BM 128
#define BN 128
#define BK 64

__device__ inline unsigned short f2bf_rne(float f) {
    unsigned int u = __builtin_bit_cast(unsigned int, f);
    u += 0x7fffu + ((u >> 16) & 1u);   // round-to-nearest-even
    return (unsigned short)(u >> 16);
}

__device__ inline float gelu_erf(float x) {
    return 0.5f * x * (1.0f + erff(x * 0.7071067811865475f));
}

__device__ inline void gload_lds16(const void* g, void* l) {
    auto gp = reinterpret_cast<const __attribute__((address_space(1))) unsigned int*>(
        reinterpret_cast<uintptr_t>(g));
    auto lp = reinterpret_cast<__attribute__((address_space(3))) unsigned int*>(
        reinterpret_cast<uintptr_t>(l));
    __builtin_amdgcn_global_load_lds(gp, lp, 16, 0, 0);
}

// C = gelu(A[M,K] @ B[N,K]^T + bias), A fp32 or bf16, C bf16 or fp32.
// Grid: (N/BN, M/BM)  -- column index FAST for A-tile temporal locality.
template <bool A_IS_FP32, bool OUT_BF16>
__global__ __launch_bounds__(256, 2)
void gemm_bias_gelu(const void* __restrict__ Av,
                    const bf16_t* __restrict__ B,     // [N,K] bf16
                    const float* __restrict__ bias,   // [N]
                    void* __restrict__ Cv,            // [M,N]
                    int M, int N, int K)
{
    __shared__ __align__(16) bf16_t lA[BM * BK];   // 16 KiB
    __shared__ __align__(16) bf16_t lB[BN * BK];   // 16 KiB

    const int tid  = threadIdx.x;
    const int wave = tid >> 6;
    const int lane = tid & 63;
    const int lrow = lane & 15;   // MFMA row/col within 16
    const int quad = lane >> 4;   // k-group of 8
    const int swz  = lrow & 7;    // per-lane read swizzle (row&7 == lrow&7)

    const int col0 = blockIdx.x * BN;   // x = column blocks (fast)
    const int row0 = blockIdx.y * BM;
    const int wm = (wave >> 1) * 64;    // wave tile: 64x64
    const int wn = (wave & 1) * 64;

    // staging: lane l fetches global chunk (l&7)^(l>>3) of row (l>>3)
    const int srow = lane >> 3;                 // row within 8-row group
    const int gchk = (lane & 7) ^ srow;         // permuted global chunk

    f32x4 acc[4][4] = {};

    const bf16_t* Bt = B + (size_t)col0 * K;

    for (int k0 = 0; k0 < K; k0 += BK) {
        // ---- stage B tile: wave w covers rows [w*32, w*32+32), 4 calls x 8 rows
        {
            const bf16_t* g = Bt + (size_t)(wave * 32 + srow) * K + k0 + gchk * 8;
            bf16_t* l = lB + (wave * 32) * BK;
            #pragma unroll
            for (int c = 0; c < 4; ++c) {
                gload_lds16(g, l);
                g += (size_t)8 * K;
                l += 8 * BK;
            }
        }
        // ---- stage A tile
        if constexpr (!A_IS_FP32) {
            const bf16_t* Ab = (const bf16_t*)Av;
            const bf16_t* g = Ab + (size_t)(row0 + wave * 32 + srow) * K + k0 + gchk * 8;
            bf16_t* l = lA + (wave * 32) * BK;
            #pragma unroll
            for (int c = 0; c < 4; ++c) {
                gload_lds16(g, l);
                g += (size_t)8 * K;
                l += 8 * BK;
            }
        } else {
            // fp32 A: float4 load -> RNE bf16 -> 8B ds_write (swizzled addr).
            const float* Af = (const float*)Av;
            #pragma unroll
            for (int c = 0; c < 8; ++c) {
                const int e = c * 1024 + tid * 4;
                const int r = e >> 6;
                const int k = e & 63;
                const float4 v = *(const float4*)(Af + (size_t)(row0 + r) * K + k0 + k);
                u16x4 h;
                h.x = f2bf_rne(v.x); h.y = f2bf_rne(v.y);
                h.z = f2bf_rne(v.z); h.w = f2bf_rne(v.w);
                const int off = r * BK + (((k >> 3) ^ (r & 7)) << 3) + (k & 7);
                *(u16x4*)(lA + off) = h;
            }
        }
        __syncthreads();

        // ---- 32 MFMAs per K-iter (2 kk-steps of 16)
        #pragma unroll
        for (int kk = 0; kk < BK; kk += 32) {
            const int cks = (kk >> 3);   // base chunk of this kk-step
            bf16x8 af[4], bfr[4];
            #pragma unroll
            for (int i = 0; i < 4; ++i) {
                const int r = wm + i * 16 + lrow;
                af[i] = *(const bf16x8*)(lA + r * BK + (((cks + quad) ^ swz) << 3));
            }
            #pragma unroll
            for (int j = 0; j < 4; ++j) {
                const int r = wn + j * 16 + lrow;
                bfr[j] = *(const bf16x8*)(lB + r * BK + (((cks + quad) ^ swz) << 3));
            }
            #pragma unroll
            for (int i = 0; i < 4; ++i) {
                #pragma unroll
                for (int j = 0; j < 4; ++j)
                    acc[i][j] = __builtin_amdgcn_mfma_f32_16x16x32_bf16(af[i], bfr[j], acc[i][j], 0, 0, 0);
            }
        }
        __syncthreads();
    }

    // ---- epilogue: bias + exact-erf GELU + store.
    // C/D layout (16x16x32): col = lane&15, row = quad*4 + reg  [m89/m91]
    #pragma unroll
    for (int j = 0; j < 4; ++j) {
        const int col = col0 + wn + j * 16 + lrow;
        const float bv = bias[col];
        #pragma unroll
        for (int i = 0; i < 4; ++i) {
            const int row = row0 + wm + i * 16 + quad * 4;
            #pragma unroll
            for (int r = 0; r < 4; ++r) {
                float v = acc[i][j][r] + bv;
                v = gelu_erf(v);
                if constexpr (OUT_BF16)
                    ((unsigned short*)Cv)[(size_t)(row + r) * N + col] = f2bf_rne(v);
                else
                    ((float*)Cv)[(size_t)(row + r) * N + col] = v;
            }
        }
    }
}

__global__ void cvt_f32_to_bf16(const float* __restrict__ s,
                                unsigned short* __restrict__ d, int n4)
{
    const int i = blockIdx.x * 256 + threadIdx.x;
    if (i < n4) {
        const float4 v = ((const float4*)s)[i];
        u16x4 h;
        h.x = f2bf_rne(v.x); h.y = f2bf_rne(v.y);
        h.z = f2bf_rne(v.z); h.w = f2bf_rne(v.w);
        ((u16x4*)d)[i] = h;
    }
}

extern "C" void kernel_launch(void* const* d_in, const int* in_sizes, int n_in,
                              void* d_out, int out_size, void* d_ws, size_t ws_size,
                              hipStream_t stream)
{
    const int BATCH = 131072, OBS = 1024, H1 = 512, H2 = 512, H3 = 256;

    const float* obs = (const float*)d_in[0];
    const float* W1  = (const float*)d_in[1];
    const float* b1  = (const float*)d_in[2];
    const float* W2  = (const float*)d_in[3];
    const float* b2  = (const float*)d_in[4];
    const float* W3  = (const float*)d_in[5];
    const float* b3  = (const float*)d_in[6];
    float* out = (float*)d_out;

    // workspace layout (~258 MB): x1 | x2 | W1b | W2b | W3b
    char* ws = (char*)d_ws;
    bf16_t* x1  = (bf16_t*)ws;                                       // BATCH*H1
    bf16_t* x2  = (bf16_t*)(ws + (size_t)BATCH * H1 * 2);            // BATCH*H2
    bf16_t* w1b = (bf16_t*)(ws + (size_t)BATCH * (H1 + H2) * 2);
    bf16_t* w2b = w1b + (size_t)H1 * OBS;
    bf16_t* w3b = w2b + (size_t)H2 * H1;

    // weight fp32 -> bf16 (tiny)
    cvt_f32_to_bf16<<<dim3((H1 * OBS / 4 + 255) / 256), 256, 0, stream>>>(W1, (unsigned short*)w1b, H1 * OBS / 4);
    cvt_f32_to_bf16<<<dim3((H2 * H1 / 4 + 255) / 256), 256, 0, stream>>>(W2, (unsigned short*)w2b, H2 * H1 / 4);
    cvt_f32_to_bf16<<<dim3((H3 * H2 / 4 + 255) / 256), 256, 0, stream>>>(W3, (unsigned short*)w3b, H3 * H2 / 4);

    // L1: obs(fp32) @ W1^T -> x1 (bf16)    grid: (cols fast, rows slow)
    gemm_bias_gelu<true, true><<<dim3(H1 / BN, BATCH / BM), 256, 0, stream>>>(
        obs, w1b, b1, x1, BATCH, H1, OBS);
    // L2: x1 @ W2^T -> x2 (bf16)
    gemm_bias_gelu<false, true><<<dim3(H2 / BN, BATCH / BM), 256, 0, stream>>>(
        x1, w2b, b2, x2, BATCH, H2, H1);
    // L3: x2 @ W3^T -> out (fp32)
    gemm_bias_gelu<false, false><<<dim3(H3 / BN, BATCH / BM), 256, 0, stream>>>(
        x2, w3b, b3, out, BATCH, H3, H2);
}